// Round 2
// 163.360 us; speedup vs baseline: 1.0495x; 1.0495x over previous
//
#include <hip/hip_runtime.h>

#define T 200
#define E 64
#define TPAD 256
#define ROW 72          // bf16 elems per padded LDS row (144 B, 16B-aligned)
#define BDIM 256
#define TP 208          // padded A-tile rows for fast kernel (13 m-tiles)

typedef __bf16 bf16_t;
typedef __bf16 bf16x8 __attribute__((ext_vector_type(8)));
typedef float f32x4 __attribute__((ext_vector_type(4)));

// ---- pre-pass: emb fp32 -> bf16 into workspace (halves gather bytes) ----
__global__ __launch_bounds__(256) void emb_cvt(const float* __restrict__ src,
                                               bf16_t* __restrict__ dst, int n8) {
    const int i = blockIdx.x * 256 + threadIdx.x;
    if (i >= n8) return;
    const float4* s = (const float4*)src + (size_t)i * 2;
    const float4 a = s[0], b = s[1];
    union { bf16_t h[8]; uint4 v; } u;
    u.h[0] = (bf16_t)a.x; u.h[1] = (bf16_t)a.y; u.h[2] = (bf16_t)a.z; u.h[3] = (bf16_t)a.w;
    u.h[4] = (bf16_t)b.x; u.h[5] = (bf16_t)b.y; u.h[6] = (bf16_t)b.z; u.h[7] = (bf16_t)b.w;
    ((uint4*)dst)[i] = u.v;
}

// ---- pre-pass: fold w1 into batch-independent pieces (fp32, exact) ----
//  Ap [e][j]  = w1a + w1c            (for u = q @ Ap)
//  Ctf[j][e]  = w1b - w1c            (M^T additive part)
//  Dtf[j][e]  = w1d                  (M^T q-scaled part)
__global__ __launch_bounds__(256) void w1_cvt(const float* __restrict__ w1,
                                              float* __restrict__ Ap,
                                              float* __restrict__ Ctf,
                                              float* __restrict__ Dtf) {
    const int idx = blockIdx.x * 256 + threadIdx.x;   // 0..4095
    const int e = idx >> 6, j = idx & 63;
    const float a = w1[e * 64 + j];
    const float b = w1[(64 + e) * 64 + j];
    const float c = w1[(128 + e) * 64 + j];
    const float d = w1[(192 + e) * 64 + j];
    Ap[e * 64 + j]  = a + c;
    Ctf[j * 64 + e] = b - c;
    Dtf[j * 64 + e] = d;
}

// ================= fast kernel: 39936 B LDS -> 4 blocks/CU =================
__global__ __launch_bounds__(256, 4) void din_fast(
    const int* __restrict__ query,
    const int* __restrict__ keys,
    const bf16_t* __restrict__ emb16,
    const float* __restrict__ Ap,
    const float* __restrict__ Ctf,
    const float* __restrict__ Dtf,
    const float* __restrict__ b1,
    const float* __restrict__ w2,
    const float* __restrict__ b2,
    const float* __restrict__ dw1,
    const float* __restrict__ db1,
    const float* __restrict__ dw2,
    const float* __restrict__ db2,
    const float* __restrict__ ow,
    const float* __restrict__ ob,
    float* __restrict__ out)
{
    // manual LDS packing: total 39936 B (floor(163840/39936) = 4 blocks/CU)
    __shared__ __align__(16) char smem[39936];
    bf16_t* sK   = (bf16_t*)smem;                 // [0,29952)  208x72 bf16 A-tile
    bf16_t* sMt  = (bf16_t*)(smem + 29952);       // [29952,39168) 64x72 bf16 B-op (M^T)
    float*  sUP  = (float*)(smem + 39168);        // [39168,39680) u partials (128)
    float*  sQf  = (float*)(smem + 39680);        // [39680,39936) q fp32 (64)
    // overlays inside sMt region (dead after B-frag load barrier):
    float*  sWgt = (float*)(smem + 29952);        // 208 scores/weights
    float*  sRed = (float*)(smem + 30784);        // 8
    float*  sInt = (float*)(smem + 30816);        // 64
    float*  sD1  = (float*)(smem + 31072);        // 128
    float*  sD2  = (float*)(smem + 31584);        // 64
    float*  sIP  = (float*)(smem + 31840);        // 256 interest partials

    const int tid  = threadIdx.x;
    const int lane = tid & 63;
    const int wid  = tid >> 6;
    const int b    = blockIdx.x;
    const float b2v = b2[0];

    // ---- issue long-latency gathers first: this thread's key row (t = tid) ----
    uint4 kr[8];
    if (tid < T) {
        const int ki = keys[b * T + tid];
        const uint4* kp = (const uint4*)(emb16 + (size_t)ki * E);
        #pragma unroll
        for (int c = 0; c < 8; ++c) kr[c] = kp[c];
    } else {
        #pragma unroll
        for (int c = 0; c < 8; ++c) kr[c] = make_uint4(0u, 0u, 0u, 0u);
    }

    // ---- query row (bf16 scalar, 64 lanes = 128B coalesced) ----
    const int qi = query[b];
    if (tid < 64) sQf[tid] = (float)emb16[(size_t)qi * E + tid];
    __syncthreads();                                   // B0: sQf ready

    // ---- u partials (tid<128): u[j] = sum_e q[e] * Ap[e][j] ----
    if (tid < 128) {
        const int j = tid & 63, ec = tid >> 6;
        float au = 0.f;
        #pragma unroll
        for (int eo = 0; eo < 32; ++eo) {
            const int e = ec * 32 + eo;
            au = fmaf(sQf[e], Ap[e * 64 + j], au);
        }
        sUP[tid] = au;
    }
    // ---- build M^T directly into sMt (no transpose scratch, no w1 reads) ----
    {
        const int j = tid & 63, h = tid >> 6;          // h: 16-col chunk
        const float* cp = Ctf + j * 64 + h * 16;
        const float* dp = Dtf + j * 64 + h * 16;
        const float* qp = sQf + h * 16;
        bf16_t mo[16] __attribute__((aligned(16)));
        #pragma unroll
        for (int x = 0; x < 16; ++x)
            mo[x] = (bf16_t)fmaf(qp[x], dp[x], cp[x]);
        *(bf16x8*)&sMt[j * ROW + h * 16]     = *(bf16x8*)&mo[0];
        *(bf16x8*)&sMt[j * ROW + h * 16 + 8] = *(bf16x8*)&mo[8];
    }
    __syncthreads();                                   // B1: sUP, sMt ready

    // ---- stage k rows into sK (gathers have had B0..B1 to land) ----
    if (tid < TP) {
        uint4* dst = (uint4*)(sK + tid * ROW);
        #pragma unroll
        for (int c = 0; c < 8; ++c) dst[c] = kr[c];
    }
    __syncthreads();                                   // B2: sK ready

    // ---- MFMA score GEMM: h_pre = u + k(208x64) * M(64x64) ----
    {
        const int n    = lane & 15;
        const int quad = lane >> 4;
        float w2v[4], uv[4];
        bf16x8 bF[4][2];
        #pragma unroll
        for (int nt = 0; nt < 4; ++nt) {
            const int jj = nt * 16 + n;
            w2v[nt] = w2[jj];
            uv[nt]  = b1[jj] + sUP[jj] + sUP[64 + jj];
            bF[nt][0] = *(const bf16x8*)&sMt[jj * ROW + quad * 8];
            bF[nt][1] = *(const bf16x8*)&sMt[jj * ROW + 32 + quad * 8];
        }
        __syncthreads();                               // B3: sMt/sUP now dead -> overlays safe

        for (int mt = wid; mt < 13; mt += 4) {
            const bf16x8 a0 = *(const bf16x8*)&sK[(mt * 16 + n) * ROW + quad * 8];
            const bf16x8 a1 = *(const bf16x8*)&sK[(mt * 16 + n) * ROW + 32 + quad * 8];
            float s0 = 0.f, s1 = 0.f, s2 = 0.f, s3 = 0.f;
            #pragma unroll
            for (int nt = 0; nt < 4; ++nt) {
                f32x4 acc = { uv[nt], uv[nt], uv[nt], uv[nt] };
                acc = __builtin_amdgcn_mfma_f32_16x16x32_bf16(a0, bF[nt][0], acc, 0, 0, 0);
                acc = __builtin_amdgcn_mfma_f32_16x16x32_bf16(a1, bF[nt][1], acc, 0, 0, 0);
                s0 = fmaf(fmaxf(acc[0], 0.f), w2v[nt], s0);
                s1 = fmaf(fmaxf(acc[1], 0.f), w2v[nt], s1);
                s2 = fmaf(fmaxf(acc[2], 0.f), w2v[nt], s2);
                s3 = fmaf(fmaxf(acc[3], 0.f), w2v[nt], s3);
            }
            #pragma unroll
            for (int off = 1; off < 16; off <<= 1) {
                s0 += __shfl_xor(s0, off);
                s1 += __shfl_xor(s1, off);
                s2 += __shfl_xor(s2, off);
                s3 += __shfl_xor(s3, off);
            }
            if (n == 0) {
                const int base = mt * 16 + quad * 4;
                sWgt[base + 0] = s0;
                sWgt[base + 1] = s1;
                sWgt[base + 2] = s2;
                sWgt[base + 3] = s3;
            }
        }
    }
    __syncthreads();                                   // B4

    // ---- softmax over t ----
    {
        const float score = (tid < T) ? (sWgt[tid] + b2v) : -1e30f;
        float m = score;
        #pragma unroll
        for (int off = 32; off > 0; off >>= 1) m = fmaxf(m, __shfl_xor(m, off));
        if (lane == 0) sRed[wid] = m;
        __syncthreads();                               // B5
        const float gmax = fmaxf(fmaxf(sRed[0], sRed[1]), fmaxf(sRed[2], sRed[3]));
        const float p = (tid < T) ? __expf(score - gmax) : 0.f;
        float s = p;
        #pragma unroll
        for (int off = 32; off > 0; off >>= 1) s += __shfl_xor(s, off);
        if (lane == 0) sRed[4 + wid] = s;
        __syncthreads();                               // B6
        const float gsum = sRed[4] + sRed[5] + sRed[6] + sRed[7];
        if (tid < T) sWgt[tid] = p / gsum;
    }
    __syncthreads();                                   // B7

    // ---- interest[e] = sum_t w[t] * k[t][e]  (t<200 only, 4x50 chunks) ----
    {
        const int e = tid & 63, ch = tid >> 6;
        float a = 0.f;
        #pragma unroll 10
        for (int tt = 0; tt < 50; ++tt) {
            const int t = ch * 50 + tt;
            a = fmaf(sWgt[t], (float)sK[t * ROW + e], a);
        }
        sIP[tid] = a;
    }
    __syncthreads();                                   // B8
    if (tid < 64) sInt[tid] = sIP[tid] + sIP[64 + tid] + sIP[128 + tid] + sIP[192 + tid];
    __syncthreads();                                   // B9

    // ---- deep MLP: 64 -> 128 -> 64 -> 1 ----
    if (tid < 128) {
        float a = db1[tid];
        #pragma unroll 8
        for (int e = 0; e < 64; ++e) a = fmaf(sInt[e], dw1[e * 128 + tid], a);
        sD1[tid] = fmaxf(a, 0.f);
    }
    __syncthreads();                                   // B10
    if (tid < 64) {
        float a = db2[tid];
        #pragma unroll 8
        for (int i = 0; i < 128; ++i) a = fmaf(sD1[i], dw2[i * 64 + tid], a);
        sD2[tid] = fmaxf(a, 0.f);
    }
    __syncthreads();                                   // B11
    if (tid < 64) {
        float v = sD2[tid] * ow[tid];
        #pragma unroll
        for (int off = 32; off > 0; off >>= 1) v += __shfl_xor(v, off);
        if (tid == 0) out[b] = 1.f / (1.f + __expf(-(v + ob[0])));
    }
}

// ============ fallback: previous verified kernel (ws too small) ============
__global__ __launch_bounds__(BDIM, 3) void din_kernel(
    const int* __restrict__ query,
    const int* __restrict__ keys,
    const float* __restrict__ embf,
    const bf16_t* __restrict__ emb16,
    const int use16,
    const float* __restrict__ w1,
    const float* __restrict__ b1,
    const float* __restrict__ w2,
    const float* __restrict__ b2,
    const float* __restrict__ dw1,
    const float* __restrict__ db1,
    const float* __restrict__ dw2,
    const float* __restrict__ db2,
    const float* __restrict__ ow,
    const float* __restrict__ ob,
    float* __restrict__ out)
{
    __shared__ __align__(16) char sRaw[TPAD * ROW * 2];
    __shared__ __align__(16) bf16_t sMt[64 * ROW];
    __shared__ float sU[64];
    __shared__ float sUP[256];
    __shared__ float sW2f[64];
    __shared__ float sWgt[256];
    __shared__ float sQf[64];
    __shared__ __align__(16) char sQtmp[128];
    __shared__ float sRed[8];
    __shared__ float sInt[64];
    __shared__ float sD1[128];
    __shared__ float sD2[64];

    const int tid  = threadIdx.x;
    const int lane = tid & 63;
    const int wid  = tid >> 6;
    const int b    = blockIdx.x;
    const float b2v = b2[0];

    uint4 kr[8];
    if (tid < T) {
        const int ki = keys[b * T + tid];
        if (use16) {
            const uint4* kp = (const uint4*)(emb16 + (size_t)ki * E);
            #pragma unroll
            for (int c = 0; c < 8; ++c) kr[c] = kp[c];
        } else {
            const float4* kp = (const float4*)(embf + (size_t)ki * E);
            #pragma unroll
            for (int c = 0; c < 8; ++c) {
                const float4 x = kp[2 * c], y = kp[2 * c + 1];
                union { bf16_t h[8]; uint4 v; } u;
                u.h[0] = (bf16_t)x.x; u.h[1] = (bf16_t)x.y; u.h[2] = (bf16_t)x.z; u.h[3] = (bf16_t)x.w;
                u.h[4] = (bf16_t)y.x; u.h[5] = (bf16_t)y.y; u.h[6] = (bf16_t)y.z; u.h[7] = (bf16_t)y.w;
                kr[c] = u.v;
            }
        }
    } else {
        #pragma unroll
        for (int c = 0; c < 8; ++c) kr[c] = make_uint4(0u, 0u, 0u, 0u);
    }

    const int qi = query[b];
    if (tid < 8) {
        uint4 qv;
        if (use16) {
            qv = ((const uint4*)(emb16 + (size_t)qi * E))[tid];
        } else {
            const float4 x = ((const float4*)(embf + (size_t)qi * E))[2 * tid];
            const float4 y = ((const float4*)(embf + (size_t)qi * E))[2 * tid + 1];
            union { bf16_t h[8]; uint4 v; } u;
            u.h[0] = (bf16_t)x.x; u.h[1] = (bf16_t)x.y; u.h[2] = (bf16_t)x.z; u.h[3] = (bf16_t)x.w;
            u.h[4] = (bf16_t)y.x; u.h[5] = (bf16_t)y.y; u.h[6] = (bf16_t)y.z; u.h[7] = (bf16_t)y.w;
            qv = u.v;
        }
        ((uint4*)sQtmp)[tid] = qv;
    }
    if (tid < 64) sW2f[tid] = w2[tid];
    __syncthreads();
    if (tid < 64) sQf[tid] = (float)((const bf16_t*)sQtmp)[tid];
    __syncthreads();

    {
        float* sTmp = (float*)sRaw;
        const int j = tid & 63, ec = tid >> 6;
        float au = 0.f;
        #pragma unroll
        for (int eo = 0; eo < 16; ++eo) {
            const int e = ec * 16 + eo;
            const float w1a = w1[e * 64 + j];
            const float w1b = w1[(64 + e) * 64 + j];
            const float w1c = w1[(128 + e) * 64 + j];
            const float w1d = w1[(192 + e) * 64 + j];
            sTmp[e * 65 + j] = w1b - w1c + sQf[e] * w1d;
            au = fmaf(sQf[e], w1a + w1c, au);
        }
        sUP[tid] = au;
    }
    __syncthreads();
    {
        const float* sTmp = (const float*)sRaw;
        const int e = tid & 63, jc = tid >> 6;
        #pragma unroll
        for (int jo = 0; jo < 16; ++jo) {
            const int j = jc * 16 + jo;
            sMt[j * ROW + e] = (bf16_t)sTmp[e * 65 + j];
        }
    }
    if (tid < 64) sU[tid] = b1[tid] + sUP[tid] + sUP[64 + tid] + sUP[128 + tid] + sUP[192 + tid];
    __syncthreads();

    bf16_t* sK = (bf16_t*)sRaw;
    {
        uint4* dst = (uint4*)(sK + tid * ROW);
        #pragma unroll
        for (int c = 0; c < 8; ++c) dst[c] = kr[c];
    }
    __syncthreads();

    {
        const int n    = lane & 15;
        const int quad = lane >> 4;
        float w2v[4], uv[4];
        bf16x8 bF[4][2];
        #pragma unroll
        for (int nt = 0; nt < 4; ++nt) {
            w2v[nt] = sW2f[nt * 16 + n];
            uv[nt]  = sU[nt * 16 + n];
            bF[nt][0] = *(const bf16x8*)&sMt[(nt * 16 + n) * ROW + quad * 8];
            bF[nt][1] = *(const bf16x8*)&sMt[(nt * 16 + n) * ROW + 32 + quad * 8];
        }
        #pragma unroll
        for (int i = 0; i < 4; ++i) {
            const int mt = wid * 4 + i;
            const bf16x8 a0 = *(const bf16x8*)&sK[(mt * 16 + n) * ROW + quad * 8];
            const bf16x8 a1 = *(const bf16x8*)&sK[(mt * 16 + n) * ROW + 32 + quad * 8];
            float s0 = 0.f, s1 = 0.f, s2 = 0.f, s3 = 0.f;
            #pragma unroll
            for (int nt = 0; nt < 4; ++nt) {
                f32x4 acc = { uv[nt], uv[nt], uv[nt], uv[nt] };
                acc = __builtin_amdgcn_mfma_f32_16x16x32_bf16(a0, bF[nt][0], acc, 0, 0, 0);
                acc = __builtin_amdgcn_mfma_f32_16x16x32_bf16(a1, bF[nt][1], acc, 0, 0, 0);
                s0 = fmaf(fmaxf(acc[0], 0.f), w2v[nt], s0);
                s1 = fmaf(fmaxf(acc[1], 0.f), w2v[nt], s1);
                s2 = fmaf(fmaxf(acc[2], 0.f), w2v[nt], s2);
                s3 = fmaf(fmaxf(acc[3], 0.f), w2v[nt], s3);
            }
            #pragma unroll
            for (int off = 1; off < 16; off <<= 1) {
                s0 += __shfl_xor(s0, off);
                s1 += __shfl_xor(s1, off);
                s2 += __shfl_xor(s2, off);
                s3 += __shfl_xor(s3, off);
            }
            if (n == 0) {
                const int base = mt * 16 + quad * 4;
                sWgt[base + 0] = s0;
                sWgt[base + 1] = s1;
                sWgt[base + 2] = s2;
                sWgt[base + 3] = s3;
            }
        }
    }
    __syncthreads();

    {
        const float score = (tid < T) ? (sWgt[tid] + b2v) : -1e30f;
        float m = score;
        #pragma unroll
        for (int off = 32; off > 0; off >>= 1) m = fmaxf(m, __shfl_xor(m, off));
        if (lane == 0) sRed[wid] = m;
        __syncthreads();
        const float gmax = fmaxf(fmaxf(sRed[0], sRed[1]), fmaxf(sRed[2], sRed[3]));
        const float p = (tid < T) ? __expf(score - gmax) : 0.f;
        float s = p;
        #pragma unroll
        for (int off = 32; off > 0; off >>= 1) s += __shfl_xor(s, off);
        if (lane == 0) sRed[4 + wid] = s;
        __syncthreads();
        const float gsum = sRed[4] + sRed[5] + sRed[6] + sRed[7];
        sWgt[tid] = p / gsum;
    }
    __syncthreads();

    {
        const int e = tid & 63, ch = tid >> 6;
        float a = 0.f;
        #pragma unroll 8
        for (int tt = 0; tt < 64; ++tt) {
            const int t = ch * 64 + tt;
            a = fmaf(sWgt[t], (float)sK[t * ROW + e], a);
        }
        sUP[tid] = a;
    }
    __syncthreads();
    if (tid < 64) sInt[tid] = sUP[tid] + sUP[64 + tid] + sUP[128 + tid] + sUP[192 + tid];
    __syncthreads();

    if (tid < 128) {
        float a = db1[tid];
        #pragma unroll 8
        for (int e = 0; e < 64; ++e) a = fmaf(sInt[e], dw1[e * 128 + tid], a);
        sD1[tid] = fmaxf(a, 0.f);
    }
    __syncthreads();
    if (tid < 64) {
        float a = db2[tid];
        #pragma unroll 8
        for (int i = 0; i < 128; ++i) a = fmaf(sD1[i], dw2[i * 64 + tid], a);
        sD2[tid] = fmaxf(a, 0.f);
    }
    __syncthreads();
    if (tid < 64) {
        float v = sD2[tid] * ow[tid];
        #pragma unroll
        for (int off = 32; off > 0; off >>= 1) v += __shfl_xor(v, off);
        if (tid == 0) out[b] = 1.f / (1.f + __expf(-(v + ob[0])));
    }
}

extern "C" void kernel_launch(void* const* d_in, const int* in_sizes, int n_in,
                              void* d_out, int out_size, void* d_ws, size_t ws_size,
                              hipStream_t stream) {
    const int*   query = (const int*)d_in[0];
    const int*   keys  = (const int*)d_in[1];
    const float* embf  = (const float*)d_in[2];
    const float* w1    = (const float*)d_in[3];
    const float* b1    = (const float*)d_in[4];
    const float* w2    = (const float*)d_in[5];
    const float* b2    = (const float*)d_in[6];
    const float* dw1   = (const float*)d_in[7];
    const float* db1   = (const float*)d_in[8];
    const float* dw2   = (const float*)d_in[9];
    const float* db2   = (const float*)d_in[10];
    const float* ow    = (const float*)d_in[11];
    const float* ob    = (const float*)d_in[12];
    float* out = (float*)d_out;
    const int B        = in_sizes[0];
    const int embElems = in_sizes[2];                  // VOCAB * E
    const size_t WOFF  = 49152;                        // Ap 16K | Ctf 16K | Dtf 16K

    if (ws_size >= WOFF + (size_t)embElems * 2) {
        float*  Ap    = (float*)d_ws;
        float*  Ctf   = (float*)((char*)d_ws + 16384);
        float*  Dtf   = (float*)((char*)d_ws + 32768);
        bf16_t* emb16 = (bf16_t*)((char*)d_ws + WOFF);
        const int n8 = embElems / 8;
        w1_cvt<<<16, 256, 0, stream>>>(w1, Ap, Ctf, Dtf);
        emb_cvt<<<(n8 + 255) / 256, 256, 0, stream>>>(embf, emb16, n8);
        din_fast<<<B, BDIM, 0, stream>>>(query, keys, emb16, Ap, Ctf, Dtf,
                                         b1, w2, b2, dw1, db1, dw2, db2, ow, ob, out);
    } else {
        const int use16 = (ws_size >= (size_t)embElems * 2) ? 1 : 0;
        bf16_t* emb16 = (bf16_t*)d_ws;
        if (use16) {
            const int n8 = embElems / 8;
            emb_cvt<<<(n8 + 255) / 256, 256, 0, stream>>>(embf, emb16, n8);
        }
        din_kernel<<<B, BDIM, 0, stream>>>(query, keys, embf, emb16, use16,
                                           w1, b1, w2, b2, dw1, db1, dw2, db2, ow, ob, out);
    }
}